// Round 7
// baseline (283.601 us; speedup 1.0000x reference)
//
#include <hip/hip_runtime.h>
#include <hip/hip_bf16.h>
#include <math.h>

// Problem constants
#define B_   16
#define D_   512
#define T_   2048
#define K_   8
#define C_   1024
#define CH_  64
#define NEL_ (B_ * D_ * T_)        // 16777216
#define QOFF 16777216              // out: [quantized | commit | ppl[8]]

// ws layout
#define WS_HCN   0                          // float[K*C]   32 KB (0.5*||c||^2)
#define WS_CNT   32768                      // int[K*C]     32 KB
#define WS_SSE   65536                      // double       8 B
#define WS_CBS   66048                      // swizzled bf16 hi/lo image, 8192 rows * 256 B = 2 MB
// image: row r (= k*1024+c) at WS_CBS + r*256; 16B group s at (s^(r&15))*16
// group s<8: hi bf16 of ch 8s..8s+7 (negated); s>=8: lo bf16 of ch 8(s-8)..

typedef __attribute__((ext_vector_type(8))) short   short8;
typedef __attribute__((ext_vector_type(8))) __bf16  bf16x8;
typedef __attribute__((ext_vector_type(4))) float   f32x4;

__device__ __forceinline__ unsigned short f2bf_rne(float f) {
    unsigned u = __builtin_bit_cast(unsigned, f);
    u = u + 0x7FFFu + ((u >> 16) & 1u);
    return (unsigned short)(u >> 16);
}
__device__ __forceinline__ float bf2f(unsigned short h) {
    unsigned u = ((unsigned)h) << 16;
    return __builtin_bit_cast(float, u);
}

__device__ __forceinline__ void gload_lds16(const void* gsrc, void* ldst) {
    __builtin_amdgcn_global_load_lds(
        (const __attribute__((address_space(1))) unsigned int*)gsrc,
        (__attribute__((address_space(3))) unsigned int*)ldst,
        16, 0, 0);
}

// ---------------------------------------------------------------------------
// Prep: build swizzled bf16 hi/lo image of (-c) + 0.5*||c||^2.
// ---------------------------------------------------------------------------
__global__ void vq_prep(const float* __restrict__ cb,
                        unsigned char* __restrict__ cbS,
                        float* __restrict__ hcn) {
    int g   = blockIdx.x * 256 + threadIdx.x;
    int row = g >> 4;
    int s16 = g & 15;
    const float* src = cb + (size_t)row * CH_;

    int  chBase = (s16 & 7) * 8;
    bool isHi   = s16 < 8;
    short8 val;
#pragma unroll
    for (int j = 0; j < 8; ++j) {
        float v  = src[chBase + j];
        float nv = -v;
        unsigned short h = f2bf_rne(nv);
        val[j] = (short)(isHi ? h : f2bf_rne(nv - bf2f(h)));
    }
    *(short8*)(cbS + (size_t)row * 256 + ((s16 ^ (row & 15)) * 16)) = val;

    if (s16 == 0) {
        float s = 0.f;
#pragma unroll 8
        for (int ch = 0; ch < CH_; ++ch) {
            float v = src[ch];
            s = fmaf(v, v, s);
        }
        hcn[row] = 0.5f * s;
    }
}

// ---------------------------------------------------------------------------
// Main. Block = 256 (4 waves), wave owns 64 t's of one (b,k). Grid = 1024
// (= exactly 4 blocks/CU resident at 36 KB LDS).
// Staging: swizzled image, global_load_lds 16B, double buffer (R6-proven).
// Argmin: quartet-submin top-2 (plain fminf on raw scores + R2-style
// value/index cndmask tracking — NO bit-packing). Epilogue rescany 8 codes
// (top-2 quartets x 4) in fp32; fp64 only for SSE accumulation.
// ---------------------------------------------------------------------------
#define LDSBUF 16384

__global__ __launch_bounds__(256, 4) void vq_main(
    const float* __restrict__ x,
    const float* __restrict__ cb,
    const unsigned char* __restrict__ cbS,
    const float* __restrict__ hcn,
    float* __restrict__ out,
    int* __restrict__ counts,
    double* __restrict__ sse)
{
    __shared__ __align__(16) unsigned char lds[2 * LDSBUF + 4096];
    float* hcnS = (float*)(lds + 2 * LDSBUF);

    const int tid  = threadIdx.x;
    const int lane = tid & 63;
    const int wave = tid >> 6;
    const int ln   = lane & 15;
    const int q    = lane >> 4;
    const int q4   = q * 4;

    const int bid = blockIdx.x;
    const int tc  = bid & 7;           // 8 t-chunks of 256
    const int k   = (bid >> 3) & 7;
    const int b   = bid >> 6;
    const int t0  = tc * 256 + wave * 64;

    // ---- B fragments (queries), bf16 hi/lo, in VGPRs: 4 t-tiles ----
    short8 bh[4][2], bl[4][2];   // [tt][kstep]
#pragma unroll
    for (int tt = 0; tt < 4; ++tt) {
        int t = t0 + tt * 16 + ln;
#pragma unroll
        for (int ks = 0; ks < 2; ++ks) {
            const float* xp = x + ((size_t)(b * D_ + k * CH_ + ks * 32 + q * 8)) * T_ + t;
            short8 sh, sl;
#pragma unroll
            for (int j = 0; j < 8; ++j) {
                float v = xp[(size_t)j * T_];
                unsigned short h = f2bf_rne(v);
                unsigned short l = f2bf_rne(v - bf2f(h));
                sh[j] = (short)h;
                sl[j] = (short)l;
            }
            bh[tt][ks] = sh;
            bl[tt][ks] = sl;
        }
    }

    const unsigned char* cbS_k = cbS + (size_t)k * C_ * 256;
    const float*         hcn_k = hcn + k * C_;

    // Stage hcn (4 KB) once via plain LDS writes (visible at first barrier).
    for (int i = tid; i < C_; i += 256) hcnS[i] = hcn_k[i];

    // Stage chunk 0 into buf0: each wave 4 x 1 KB async.
    {
        const unsigned char* src = cbS_k + wave * 4096 + lane * 16;
        unsigned char* dst = lds + wave * 4096;
#pragma unroll
        for (int i = 0; i < 4; ++i)
            gload_lds16(src + i * 1024, dst + i * 1024);
    }

    // Quartet-submin top-2 per t-tile: value + sub-index j (= chunk*4+sub).
    // Lane's quartet for sub j: codes j*16 + q*4 + {0..3}  (quartet id j*4+q).
    float md1[4], md2[4];
    int   mj1[4], mj2[4];
#pragma unroll
    for (int tt = 0; tt < 4; ++tt) {
        md1[tt] = INFINITY; md2[tt] = INFINITY;
        mj1[tt] = 0;        mj2[tt] = 0;
    }

    for (int chunk = 0; chunk < 16; ++chunk) {
        __syncthreads();   // drains this chunk's async loads (+hcnS on iter 0)

        if (chunk < 15) {  // prefetch next chunk into the other buffer
            const unsigned char* src =
                cbS_k + (size_t)(chunk + 1) * 16384 + wave * 4096 + lane * 16;
            unsigned char* dst = lds + ((chunk + 1) & 1) * LDSBUF + wave * 4096;
#pragma unroll
            for (int i = 0; i < 4; ++i)
                gload_lds16(src + i * 1024, dst + i * 1024);
        }

        const unsigned char* buf = lds + (chunk & 1) * LDSBUF;
#pragma unroll
        for (int sub = 0; sub < 4; ++sub) {
            const unsigned char* rowb = buf + (sub * 16 + ln) * 256;
            f32x4 h4 = *(const f32x4*)(hcnS + chunk * 64 + sub * 16 + q4);
            f32x4 a[4];
#pragma unroll
            for (int tt = 0; tt < 4; ++tt) a[tt] = h4;
#pragma unroll
            for (int ks = 0; ks < 2; ++ks) {
                int cidx = ((ks * 4 + q) ^ ln) * 16;
                bf16x8 ah = __builtin_bit_cast(bf16x8, *(const short8*)(rowb + cidx));
                bf16x8 al = __builtin_bit_cast(bf16x8, *(const short8*)(rowb + (cidx ^ 128)));
#pragma unroll
                for (int tt = 0; tt < 4; ++tt)
                    a[tt] = __builtin_amdgcn_mfma_f32_16x16x32_bf16(ah, __builtin_bit_cast(bf16x8, bh[tt][ks]), a[tt], 0, 0, 0);
#pragma unroll
                for (int tt = 0; tt < 4; ++tt)
                    a[tt] = __builtin_amdgcn_mfma_f32_16x16x32_bf16(ah, __builtin_bit_cast(bf16x8, bl[tt][ks]), a[tt], 0, 0, 0);
#pragma unroll
                for (int tt = 0; tt < 4; ++tt)
                    a[tt] = __builtin_amdgcn_mfma_f32_16x16x32_bf16(al, __builtin_bit_cast(bf16x8, bh[tt][ks]), a[tt], 0, 0, 0);
            }
            const int j = chunk * 4 + sub;
#pragma unroll
            for (int tt = 0; tt < 4; ++tt) {
                float v = fminf(fminf(a[tt][0], a[tt][1]),
                                fminf(a[tt][2], a[tt][3]));
                bool w1 = v < md1[tt];
                bool w2 = v < md2[tt];
                float nmd2 = w1 ? md1[tt] : (w2 ? v : md2[tt]);
                int   nmj2 = w1 ? mj1[tt] : (w2 ? j : mj2[tt]);
                md1[tt] = w1 ? v : md1[tt];
                mj1[tt] = w1 ? j : mj1[tt];
                md2[tt] = nmd2;
                mj2[tt] = nmj2;
            }
        }
    }

    // ---- Epilogue ----
    double waveSse = 0.0;
    const float* cb_k = cb + (size_t)k * C_ * CH_;

#pragma unroll
    for (int tt = 0; tt < 4; ++tt) {
        const int t = t0 + tt * 16 + ln;

        // (value, quartet-id) pairs; quartet id g = j*4 + q covers codes
        // g*4 + {0..3}. Cross-lane top-2 merge over q (xor 16, 32), R2-style.
        float d1 = md1[tt], d2 = md2[tt];
        int   g1 = mj1[tt] * 4 + q, g2 = mj2[tt] * 4 + q;
#pragma unroll
        for (int off = 16; off <= 32; off <<= 1) {
            float od1 = __shfl_xor(d1, off);
            int   og1 = __shfl_xor(g1, off);
            float od2 = __shfl_xor(d2, off);
            int   og2 = __shfl_xor(g2, off);
            if (od1 < d1) {
                float nd2 = (d1 < od2) ? d1 : od2;
                int   ng2 = (d1 < od2) ? g1 : og2;
                d1 = od1; g1 = og1; d2 = nd2; g2 = ng2;
            } else {
                float nd2 = (od1 < d2) ? od1 : d2;
                int   ng2 = (od1 < d2) ? og1 : g2;
                d2 = nd2; g2 = ng2;
            }
        }

        // fp32 rescore of the 8 candidate codes (2 quartets x 4 via q).
        const int c0 = g1 * 4 + q;          // this lane's code from quartet 1
        const int c1 = g2 * 4 + q;          // ... from quartet 2
        const float* r0 = cb_k + (size_t)c0 * CH_;
        const float* r1 = cb_k + (size_t)c1 * CH_;
        const float* xcol = x + ((size_t)(b * D_ + k * CH_)) * T_ + t;
        float s0 = 0.f, s1 = 0.f;
#pragma unroll 8
        for (int ch = 0; ch < CH_; ++ch) {
            float xv = xcol[(size_t)ch * T_];
            float e0 = xv - r0[ch]; s0 = fmaf(e0, e0, s0);
            float e1 = xv - r1[ch]; s1 = fmaf(e1, e1, s1);
        }
        // In-lane pick with index tie-break (np first-occurrence).
        bool p1 = (s1 < s0) || (s1 == s0 && c1 < c0);
        float sv = p1 ? s1 : s0;
        int   sc = p1 ? c1 : c0;
        // Cross-q merge (tie-robust: value then index) — all lanes converge.
#pragma unroll
        for (int off = 16; off <= 32; off <<= 1) {
            float ov = __shfl_xor(sv, off);
            int   oc = __shfl_xor(sc, off);
            bool w = (ov < sv) || (ov == sv && oc < sc);
            sv = w ? ov : sv;
            sc = w ? oc : sc;
        }
        const int idx = sc;

        if (q == 0) {                       // one vote per query
            waveSse += (double)sv;          // ||x - q||^2 (fp32 -> fp64 acc)
            atomicAdd(&counts[k * C_ + idx], 1);
        }

        // Quantized write: lane covers ch = q*16 .. q*16+15, column t.
        const float* qrow = cb_k + (size_t)idx * CH_ + q * 16;
        float* op = out + ((size_t)(b * D_ + k * CH_ + q * 16)) * T_ + t;
#pragma unroll
        for (int jj = 0; jj < 4; ++jj) {
            float4 qv = *(const float4*)(qrow + 4 * jj);
            op[(size_t)(4 * jj + 0) * T_] = qv.x;
            op[(size_t)(4 * jj + 1) * T_] = qv.y;
            op[(size_t)(4 * jj + 2) * T_] = qv.z;
            op[(size_t)(4 * jj + 3) * T_] = qv.w;
        }
    }

    // One fp64 atomic per wave.
    for (int off = 32; off > 0; off >>= 1) waveSse += __shfl_down(waveSse, off);
    if (lane == 0) atomicAdd(sse, waveSse);
}

// ---------------------------------------------------------------------------
// Finalize: one block per k -> perplexity; block 0 also writes commit loss.
// ---------------------------------------------------------------------------
__global__ void vq_final(const int* __restrict__ counts,
                         const double* __restrict__ sse,
                         float* __restrict__ out) {
    __shared__ double part[4];
    const int tid = threadIdx.x;
    const int k   = blockIdx.x;
    double local = 0.0;
    for (int j = tid; j < C_; j += 256) {
        double p = (double)counts[k * C_ + j] * (1.0 / (double)(B_ * T_));
        local += -p * log(p + 1e-8);
    }
    for (int off = 32; off > 0; off >>= 1) local += __shfl_down(local, off);
    if ((tid & 63) == 0) part[tid >> 6] = local;
    __syncthreads();
    if (tid == 0) {
        double sum = part[0] + part[1] + part[2] + part[3];
        out[QOFF + 1 + k] = (float)exp(sum);
        if (k == 0)
            out[QOFF] = (float)(1.25 * (*sse) / (double)NEL_);
    }
}

// ---------------------------------------------------------------------------
extern "C" void kernel_launch(void* const* d_in, const int* in_sizes, int n_in,
                              void* d_out, int out_size, void* d_ws, size_t ws_size,
                              hipStream_t stream) {
    const float* x  = (const float*)d_in[0];
    const float* cb = (const float*)d_in[1];
    float* out = (float*)d_out;

    float*         hcn    = (float*)((char*)d_ws + WS_HCN);
    int*           counts = (int*)((char*)d_ws + WS_CNT);
    double*        sse    = (double*)((char*)d_ws + WS_SSE);
    unsigned char* cbS    = (unsigned char*)((char*)d_ws + WS_CBS);

    hipMemsetAsync((char*)d_ws + WS_CNT, 0, 33024, stream);  // counts + sse

    vq_prep<<<(K_ * C_ * 16) / 256, 256, 0, stream>>>(cb, cbS, hcn);
    vq_main<<<B_ * K_ * (T_ / 256), 256, 0, stream>>>(x, cb, cbS, hcn,
                                                      out, counts, sse);
    vq_final<<<K_, 256, 0, stream>>>(counts, sse, out);
}

// Round 8
// 236.961 us; speedup vs baseline: 1.1968x; 1.1968x over previous
//
#include <hip/hip_runtime.h>
#include <hip/hip_bf16.h>
#include <math.h>

// Problem constants
#define B_   16
#define D_   512
#define T_   2048
#define K_   8
#define C_   1024
#define CH_  64
#define NEL_ (B_ * D_ * T_)        // 16777216
#define QOFF 16777216              // out: [quantized | commit | ppl[8]]

// ws layout
#define WS_HCN   0                          // float[K*C]   32 KB (0.5*||c||^2)
#define WS_CNT   32768                      // int[K*C]     32 KB
#define WS_SSE   65536                      // double       8 B
#define WS_CBS   66048                      // swizzled bf16 (hi only) image, 8192 rows * 128 B = 1 MB
// image: row r (= k*1024+c) at WS_CBS + r*128; 16B group s (s=0..7, ch 8s..8s+7,
// negated bf16) stored at ((s ^ (r & 7)) * 16).

typedef __attribute__((ext_vector_type(8))) short   short8;
typedef __attribute__((ext_vector_type(8))) __bf16  bf16x8;
typedef __attribute__((ext_vector_type(4))) float   f32x4;

__device__ __forceinline__ unsigned short f2bf_rne(float f) {
    unsigned u = __builtin_bit_cast(unsigned, f);
    u = u + 0x7FFFu + ((u >> 16) & 1u);
    return (unsigned short)(u >> 16);
}

__device__ __forceinline__ void gload_lds16(const void* gsrc, void* ldst) {
    __builtin_amdgcn_global_load_lds(
        (const __attribute__((address_space(1))) unsigned int*)gsrc,
        (__attribute__((address_space(3))) unsigned int*)ldst,
        16, 0, 0);
}

// ---------------------------------------------------------------------------
// Prep: swizzled bf16 (hi-only) image of (-c) + 0.5*||c||^2.
// One thread per 16B group: g = row*8 + s. 65536 threads.
// ---------------------------------------------------------------------------
__global__ void vq_prep(const float* __restrict__ cb,
                        unsigned char* __restrict__ cbS,
                        float* __restrict__ hcn) {
    int g   = blockIdx.x * 256 + threadIdx.x;
    int row = g >> 3;
    int s8  = g & 7;
    const float* src = cb + (size_t)row * CH_;

    short8 val;
#pragma unroll
    for (int j = 0; j < 8; ++j)
        val[j] = (short)f2bf_rne(-src[s8 * 8 + j]);
    *(short8*)(cbS + (size_t)row * 128 + ((s8 ^ (row & 7)) * 16)) = val;

    if (s8 == 0) {
        float s = 0.f;
#pragma unroll 8
        for (int ch = 0; ch < CH_; ++ch) {
            float v = src[ch];
            s = fmaf(v, v, s);
        }
        hcn[row] = 0.5f * s;
    }
}

// ---------------------------------------------------------------------------
// Main. Block = 256 (4 waves), wave owns 32 t's of one (b,k). Grid = 2048.
// Staging: swizzled hi-only image, global_load_lds 16B, double buffer.
// Chunk = 128 codes (16 KB). Argmin/epilogue: R6 VERBATIM (proven):
// per-slot strict-< value/index tracking, xor-16/32 top-2 merge,
// distributed fp64 rescore, q==0 global atomic counts.
// ---------------------------------------------------------------------------
#define LDSBUF 16384

__global__ __launch_bounds__(256) void vq_main(
    const float* __restrict__ x,
    const float* __restrict__ cb,
    const unsigned char* __restrict__ cbS,
    const float* __restrict__ hcn,
    float* __restrict__ out,
    int* __restrict__ counts,
    double* __restrict__ sse)
{
    __shared__ __align__(16) unsigned char lds[2 * LDSBUF + 4096];
    float* hcnS = (float*)(lds + 2 * LDSBUF);

    const int tid  = threadIdx.x;
    const int lane = tid & 63;
    const int wave = tid >> 6;
    const int ln   = lane & 15;
    const int q    = lane >> 4;
    const int q4   = q * 4;

    const int bid = blockIdx.x;
    const int tc  = bid & 15;
    const int k   = (bid >> 4) & 7;
    const int b   = bid >> 7;
    const int t0  = tc * 128 + wave * 32;

    // ---- B fragments (queries), bf16 hi only, in VGPRs ----
    short8 bh[2][2];   // [tt][kstep]
    for (int tt = 0; tt < 2; ++tt) {
        int t = t0 + tt * 16 + ln;
        for (int ks = 0; ks < 2; ++ks) {
            const float* xp = x + ((size_t)(b * D_ + k * CH_ + ks * 32 + q * 8)) * T_ + t;
            short8 sh;
#pragma unroll
            for (int j = 0; j < 8; ++j)
                sh[j] = (short)f2bf_rne(xp[(size_t)j * T_]);
            bh[tt][ks] = sh;
        }
    }

    const unsigned char* cbS_k = cbS + (size_t)k * C_ * 128;
    const float*         hcn_k = hcn + k * C_;

    // Stage hcn (4 KB) once via plain LDS writes (visible at first barrier).
    for (int i = tid; i < C_; i += 256) hcnS[i] = hcn_k[i];

    // Stage chunk 0 (128 codes, 16 KB) into buf0: each wave 4 x 1 KB async.
    {
        const unsigned char* src = cbS_k + wave * 4096 + lane * 16;
        unsigned char* dst = lds + wave * 4096;
#pragma unroll
        for (int i = 0; i < 4; ++i)
            gload_lds16(src + i * 1024, dst + i * 1024);
    }

    // Per-slot running minima (R6 verbatim). Slot (tt, r): c = j*16 + q*4 + r.
    float md[2][4];
    int   mj[2][4];
#pragma unroll
    for (int tt = 0; tt < 2; ++tt)
#pragma unroll
        for (int r = 0; r < 4; ++r) { md[tt][r] = INFINITY; mj[tt][r] = 0; }

    for (int chunk = 0; chunk < 8; ++chunk) {
        __syncthreads();   // drains this chunk's async loads (+hcnS on iter 0)

        if (chunk < 7) {   // prefetch next chunk into the other buffer
            const unsigned char* src =
                cbS_k + (size_t)(chunk + 1) * 16384 + wave * 4096 + lane * 16;
            unsigned char* dst = lds + ((chunk + 1) & 1) * LDSBUF + wave * 4096;
#pragma unroll
            for (int i = 0; i < 4; ++i)
                gload_lds16(src + i * 1024, dst + i * 1024);
        }

        const unsigned char* buf = lds + (chunk & 1) * LDSBUF;
#pragma unroll
        for (int sub = 0; sub < 8; ++sub) {
            const unsigned char* rowb = buf + (sub * 16 + ln) * 128;
            f32x4 h4 = *(const f32x4*)(hcnS + chunk * 128 + sub * 16 + q4);
            f32x4 a0 = h4, a1 = h4;
#pragma unroll
            for (int ks = 0; ks < 2; ++ks) {
                int cidx = ((ks * 4 + q) ^ (ln & 7)) * 16;
                bf16x8 ah = __builtin_bit_cast(bf16x8, *(const short8*)(rowb + cidx));
                a0 = __builtin_amdgcn_mfma_f32_16x16x32_bf16(ah, __builtin_bit_cast(bf16x8, bh[0][ks]), a0, 0, 0, 0);
                a1 = __builtin_amdgcn_mfma_f32_16x16x32_bf16(ah, __builtin_bit_cast(bf16x8, bh[1][ks]), a1, 0, 0, 0);
            }
            const int j = chunk * 8 + sub;
#pragma unroll
            for (int r = 0; r < 4; ++r) {
                bool lt0 = a0[r] < md[0][r];
                md[0][r] = lt0 ? a0[r] : md[0][r];
                mj[0][r] = lt0 ? j : mj[0][r];
                bool lt1 = a1[r] < md[1][r];
                md[1][r] = lt1 ? a1[r] : md[1][r];
                mj[1][r] = lt1 ? j : mj[1][r];
            }
        }
    }

    // ---- Epilogue (R6 verbatim) ----
    double waveSse = 0.0;
    const float* cb_k = cb + (size_t)k * C_ * CH_;

    for (int tt = 0; tt < 2; ++tt) {
        const int t = t0 + tt * 16 + ln;

        // Fold 4 slots -> in-lane top-2.
        float d1 = md[tt][0], d2 = INFINITY;
        int   c1 = mj[tt][0] * 16 + q * 4, c2 = 0;
#pragma unroll
        for (int r = 1; r < 4; ++r) {
            float v  = md[tt][r];
            int   cv = mj[tt][r] * 16 + q * 4 + r;
            bool b1 = v < d1;
            bool b2 = v < d2;
            float nd2 = b1 ? d1 : (b2 ? v : d2);
            int   nc2 = b1 ? c1 : (b2 ? cv : c2);
            d1 = b1 ? v : d1;
            c1 = b1 ? cv : c1;
            d2 = nd2; c2 = nc2;
        }
        // Cross-lane top-2 merge over q (xor 16, 32).
#pragma unroll
        for (int off = 16; off <= 32; off <<= 1) {
            float od1 = __shfl_xor(d1, off);
            int   oc1 = __shfl_xor(c1, off);
            float od2 = __shfl_xor(d2, off);
            int   oc2 = __shfl_xor(c2, off);
            if (od1 < d1) {
                float nd2 = (d1 < od2) ? d1 : od2;
                int   nc2 = (d1 < od2) ? c1 : oc2;
                d1 = od1; c1 = oc1; d2 = nd2; c2 = nc2;
            } else {
                float nd2 = (od1 < d2) ? od1 : d2;
                int   nc2 = (od1 < d2) ? oc1 : c2;
                d2 = nd2; c2 = nc2;
            }
        }

        // fp64 rescore of both candidates, distributed over lanes.
        const int half = q & 1;
        const int cc   = (lane >= 32) ? c2 : c1;
        const float* crow = cb_k + (size_t)cc * CH_ + half * 32;
        const float* xcol = x + ((size_t)(b * D_ + k * CH_ + half * 32)) * T_ + t;
        double s = 0.0;
#pragma unroll
        for (int ch = 0; ch < 32; ++ch) {
            double e = (double)xcol[(size_t)ch * T_] - (double)crow[ch];
            s = fma(e, e, s);
        }
        s += __shfl_xor(s, 16);              // combine halves (same cand)
        double so = __shfl_xor(s, 32);       // other cand's total
        double s1 = (lane < 32) ? s : so;
        double s2 = (lane < 32) ? so : s;
        bool pick2 = (s2 < s1) || (s2 == s1 && c2 < c1);
        int    idx = pick2 ? c2 : c1;
        double dm  = pick2 ? s2 : s1;        // ||x - q||^2 = SSE term

        if (q == 0) {
            waveSse += dm;
            atomicAdd(&counts[k * C_ + idx], 1);
        }

        // Quantized write: lane covers ch = q*16 .. q*16+15, column t.
        const float* qrow = cb_k + (size_t)idx * CH_ + q * 16;
        float* op = out + ((size_t)(b * D_ + k * CH_ + q * 16)) * T_ + t;
#pragma unroll
        for (int jj = 0; jj < 4; ++jj) {
            float4 qv = *(const float4*)(qrow + 4 * jj);
            op[(size_t)(4 * jj + 0) * T_] = qv.x;
            op[(size_t)(4 * jj + 1) * T_] = qv.y;
            op[(size_t)(4 * jj + 2) * T_] = qv.z;
            op[(size_t)(4 * jj + 3) * T_] = qv.w;
        }
    }

    // One fp64 atomic per wave.
    for (int off = 32; off > 0; off >>= 1) waveSse += __shfl_down(waveSse, off);
    if (lane == 0) atomicAdd(sse, waveSse);
}

// ---------------------------------------------------------------------------
// Finalize: one block per k -> perplexity; block 0 also writes commit loss.
// ---------------------------------------------------------------------------
__global__ void vq_final(const int* __restrict__ counts,
                         const double* __restrict__ sse,
                         float* __restrict__ out) {
    __shared__ double part[4];
    const int tid = threadIdx.x;
    const int k   = blockIdx.x;
    double local = 0.0;
    for (int j = tid; j < C_; j += 256) {
        double p = (double)counts[k * C_ + j] * (1.0 / (double)(B_ * T_));
        local += -p * log(p + 1e-8);
    }
    for (int off = 32; off > 0; off >>= 1) local += __shfl_down(local, off);
    if ((tid & 63) == 0) part[tid >> 6] = local;
    __syncthreads();
    if (tid == 0) {
        double sum = part[0] + part[1] + part[2] + part[3];
        out[QOFF + 1 + k] = (float)exp(sum);
        if (k == 0)
            out[QOFF] = (float)(1.25 * (*sse) / (double)NEL_);
    }
}

// ---------------------------------------------------------------------------
extern "C" void kernel_launch(void* const* d_in, const int* in_sizes, int n_in,
                              void* d_out, int out_size, void* d_ws, size_t ws_size,
                              hipStream_t stream) {
    const float* x  = (const float*)d_in[0];
    const float* cb = (const float*)d_in[1];
    float* out = (float*)d_out;

    float*         hcn    = (float*)((char*)d_ws + WS_HCN);
    int*           counts = (int*)((char*)d_ws + WS_CNT);
    double*        sse    = (double*)((char*)d_ws + WS_SSE);
    unsigned char* cbS    = (unsigned char*)((char*)d_ws + WS_CBS);

    hipMemsetAsync((char*)d_ws + WS_CNT, 0, 33024, stream);  // counts + sse

    vq_prep<<<(K_ * C_ * 8) / 256, 256, 0, stream>>>(cb, cbS, hcn);
    vq_main<<<B_ * K_ * (T_ / 128), 256, 0, stream>>>(x, cb, cbS, hcn,
                                                      out, counts, sse);
    vq_final<<<K_, 256, 0, stream>>>(counts, sse, out);
}

// Round 9
// 221.959 us; speedup vs baseline: 1.2777x; 1.0676x over previous
//
#include <hip/hip_runtime.h>
#include <hip/hip_bf16.h>
#include <math.h>

// Problem constants
#define B_   16
#define D_   512
#define T_   2048
#define K_   8
#define C_   1024
#define CH_  64
#define NEL_ (B_ * D_ * T_)        // 16777216
#define QOFF 16777216              // out: [quantized | commit | ppl[8]]

// ws layout
#define WS_HCN   0                          // float[K*C]   32 KB (0.5*||c||^2)
#define WS_CNT   32768                      // int[K*C]     32 KB
#define WS_SSE   65536                      // double       8 B
#define WS_CBS   66048                      // swizzled bf16 (hi only) image, 8192 rows * 128 B = 1 MB
// image: row r (= k*1024+c) at WS_CBS + r*128; 16B group s (s=0..7, ch 8s..8s+7,
// negated bf16) stored at ((s ^ (r & 7)) * 16).

typedef __attribute__((ext_vector_type(8))) short   short8;
typedef __attribute__((ext_vector_type(8))) __bf16  bf16x8;
typedef __attribute__((ext_vector_type(4))) float   f32x4;

__device__ __forceinline__ unsigned short f2bf_rne(float f) {
    unsigned u = __builtin_bit_cast(unsigned, f);
    u = u + 0x7FFFu + ((u >> 16) & 1u);
    return (unsigned short)(u >> 16);
}

__device__ __forceinline__ void gload_lds16(const void* gsrc, void* ldst) {
    __builtin_amdgcn_global_load_lds(
        (const __attribute__((address_space(1))) unsigned int*)gsrc,
        (__attribute__((address_space(3))) unsigned int*)ldst,
        16, 0, 0);
}

// ---------------------------------------------------------------------------
// Prep: swizzled bf16 (hi-only) image of (-c) + 0.5*||c||^2.
// One thread per 16B group: g = row*8 + s. 65536 threads.
// ---------------------------------------------------------------------------
__global__ void vq_prep(const float* __restrict__ cb,
                        unsigned char* __restrict__ cbS,
                        float* __restrict__ hcn) {
    int g   = blockIdx.x * 256 + threadIdx.x;
    int row = g >> 3;
    int s8  = g & 7;
    const float* src = cb + (size_t)row * CH_;

    short8 val;
#pragma unroll
    for (int j = 0; j < 8; ++j)
        val[j] = (short)f2bf_rne(-src[s8 * 8 + j]);
    *(short8*)(cbS + (size_t)row * 128 + ((s8 ^ (row & 7)) * 16)) = val;

    if (s8 == 0) {
        float s = 0.f;
#pragma unroll 8
        for (int ch = 0; ch < CH_; ++ch) {
            float v = src[ch];
            s = fmaf(v, v, s);
        }
        hcn[row] = 0.5f * s;
    }
}

// ---------------------------------------------------------------------------
// Main. Block = 256 (4 waves), wave owns 64 t's (4 t-tiles) of one (b,k).
// Grid = 1024 = exactly 4 blocks/CU at 36 KB LDS.
// Staging: swizzled hi-only image, global_load_lds 16B, double buffer
// (R8-proven). Argmin: per-slot strict-< value/index tracking (R6-proven
// construct), TOP-1 only. No rescore: SSE = ||x||^2 + 2*score with ||x||^2
// accumulated at load. All merges lexicographic (value, code) so the 4
// q-lanes converge bitwise on idx.
// ---------------------------------------------------------------------------
#define LDSBUF 16384

__global__ __launch_bounds__(256, 4) void vq_main(
    const float* __restrict__ x,
    const float* __restrict__ cb,
    const unsigned char* __restrict__ cbS,
    const float* __restrict__ hcn,
    float* __restrict__ out,
    int* __restrict__ counts,
    double* __restrict__ sse)
{
    __shared__ __align__(16) unsigned char lds[2 * LDSBUF + 4096];
    float* hcnS = (float*)(lds + 2 * LDSBUF);

    const int tid  = threadIdx.x;
    const int lane = tid & 63;
    const int wave = tid >> 6;
    const int ln   = lane & 15;
    const int q    = lane >> 4;
    const int q4   = q * 4;

    const int bid = blockIdx.x;
    const int tc  = bid & 7;            // 8 t-chunks of 256
    const int k   = (bid >> 3) & 7;
    const int b   = bid >> 6;
    const int t0  = tc * 256 + wave * 64;

    // ---- B fragments (queries) + ||x||^2 per query ----
    short8 bh[4][2];    // [tt][kstep]
    float  xn[4];       // ||x_t||^2 for t = t0 + tt*16 + ln (all lanes)
#pragma unroll
    for (int tt = 0; tt < 4; ++tt) {
        int t = t0 + tt * 16 + ln;
        float pn = 0.f;
#pragma unroll
        for (int ks = 0; ks < 2; ++ks) {
            const float* xp = x + ((size_t)(b * D_ + k * CH_ + ks * 32 + q * 8)) * T_ + t;
            short8 sh;
#pragma unroll
            for (int j = 0; j < 8; ++j) {
                float v = xp[(size_t)j * T_];
                pn = fmaf(v, v, pn);
                sh[j] = (short)f2bf_rne(v);
            }
            bh[tt][ks] = sh;
        }
        pn += __shfl_xor(pn, 16);       // sum the 4 q-lane partials
        pn += __shfl_xor(pn, 32);
        xn[tt] = pn;
    }

    const unsigned char* cbS_k = cbS + (size_t)k * C_ * 128;
    const float*         hcn_k = hcn + k * C_;

    // Stage hcn (4 KB) once via plain LDS writes (visible at first barrier).
    for (int i = tid; i < C_; i += 256) hcnS[i] = hcn_k[i];

    // Stage chunk 0 (128 codes, 16 KB) into buf0: each wave 4 x 1 KB async.
    {
        const unsigned char* src = cbS_k + wave * 4096 + lane * 16;
        unsigned char* dst = lds + wave * 4096;
#pragma unroll
        for (int i = 0; i < 4; ++i)
            gload_lds16(src + i * 1024, dst + i * 1024);
    }

    // Per-slot running minima (R6-proven construct). Slot (tt, r):
    // code = j*16 + q*4 + r, j = chunk*8 + sub.
    float md[4][4];
    int   mj[4][4];
#pragma unroll
    for (int tt = 0; tt < 4; ++tt)
#pragma unroll
        for (int r = 0; r < 4; ++r) { md[tt][r] = INFINITY; mj[tt][r] = 0; }

    for (int chunk = 0; chunk < 8; ++chunk) {
        __syncthreads();   // drains this chunk's async loads (+hcnS on iter 0)

        if (chunk < 7) {   // prefetch next chunk into the other buffer
            const unsigned char* src =
                cbS_k + (size_t)(chunk + 1) * 16384 + wave * 4096 + lane * 16;
            unsigned char* dst = lds + ((chunk + 1) & 1) * LDSBUF + wave * 4096;
#pragma unroll
            for (int i = 0; i < 4; ++i)
                gload_lds16(src + i * 1024, dst + i * 1024);
        }

        const unsigned char* buf = lds + (chunk & 1) * LDSBUF;
#pragma unroll
        for (int sub = 0; sub < 8; ++sub) {
            const unsigned char* rowb = buf + (sub * 16 + ln) * 128;
            f32x4 h4 = *(const f32x4*)(hcnS + chunk * 128 + sub * 16 + q4);
            f32x4 a[4];
#pragma unroll
            for (int tt = 0; tt < 4; ++tt) a[tt] = h4;
#pragma unroll
            for (int ks = 0; ks < 2; ++ks) {
                int cidx = ((ks * 4 + q) ^ (ln & 7)) * 16;
                bf16x8 ah = __builtin_bit_cast(bf16x8, *(const short8*)(rowb + cidx));
#pragma unroll
                for (int tt = 0; tt < 4; ++tt)
                    a[tt] = __builtin_amdgcn_mfma_f32_16x16x32_bf16(
                        ah, __builtin_bit_cast(bf16x8, bh[tt][ks]), a[tt], 0, 0, 0);
            }
            const int j = chunk * 8 + sub;
#pragma unroll
            for (int tt = 0; tt < 4; ++tt) {
#pragma unroll
                for (int r = 0; r < 4; ++r) {
                    bool lt = a[tt][r] < md[tt][r];
                    md[tt][r] = lt ? a[tt][r] : md[tt][r];
                    mj[tt][r] = lt ? j : mj[tt][r];
                }
            }
        }
    }

    // ---- Epilogue: top-1 consensus + SSE + counts + quantized write ----
    double waveSse = 0.0;
    const float* cb_k = cb + (size_t)k * C_ * CH_;

#pragma unroll
    for (int tt = 0; tt < 4; ++tt) {
        const int t = t0 + tt * 16 + ln;

        // Fold 4 slots -> in-lane top-1, lexicographic (value, code).
        float d1 = md[tt][0];
        int   c1 = mj[tt][0] * 16 + q4;
#pragma unroll
        for (int r = 1; r < 4; ++r) {
            float v  = md[tt][r];
            int   cv = mj[tt][r] * 16 + q4 + r;
            bool w = (v < d1) || (v == d1 && cv < c1);
            d1 = w ? v : d1;
            c1 = w ? cv : c1;
        }
        // Cross-lane top-1 merge over q (xor 16, 32), lexicographic ->
        // all 4 q-lanes converge bitwise on the same (d1, c1).
#pragma unroll
        for (int off = 16; off <= 32; off <<= 1) {
            float ov = __shfl_xor(d1, off);
            int   oc = __shfl_xor(c1, off);
            bool w = (ov < d1) || (ov == d1 && oc < c1);
            d1 = w ? ov : d1;
            c1 = w ? oc : c1;
        }
        const int idx = c1;

        if (q == 0) {                        // one vote per query
            // ||x - c||^2 = ||x||^2 + 2*(0.5||c||^2 - x.c) = xn + 2*score
            waveSse += (double)(xn[tt] + 2.0f * d1);
            atomicAdd(&counts[k * C_ + idx], 1);
        }

        // Quantized write: lane covers ch = q*16 .. q*16+15, column t.
        const float* qrow = cb_k + (size_t)idx * CH_ + q * 16;
        float* op = out + ((size_t)(b * D_ + k * CH_ + q * 16)) * T_ + t;
#pragma unroll
        for (int jj = 0; jj < 4; ++jj) {
            float4 qv = *(const float4*)(qrow + 4 * jj);
            op[(size_t)(4 * jj + 0) * T_] = qv.x;
            op[(size_t)(4 * jj + 1) * T_] = qv.y;
            op[(size_t)(4 * jj + 2) * T_] = qv.z;
            op[(size_t)(4 * jj + 3) * T_] = qv.w;
        }
    }

    // One fp64 atomic per wave.
    for (int off = 32; off > 0; off >>= 1) waveSse += __shfl_down(waveSse, off);
    if (lane == 0) atomicAdd(sse, waveSse);
}

// ---------------------------------------------------------------------------
// Finalize: one block per k -> perplexity; block 0 also writes commit loss.
// ---------------------------------------------------------------------------
__global__ void vq_final(const int* __restrict__ counts,
                         const double* __restrict__ sse,
                         float* __restrict__ out) {
    __shared__ double part[4];
    const int tid = threadIdx.x;
    const int k   = blockIdx.x;
    double local = 0.0;
    for (int j = tid; j < C_; j += 256) {
        double p = (double)counts[k * C_ + j] * (1.0 / (double)(B_ * T_));
        local += -p * log(p + 1e-8);
    }
    for (int off = 32; off > 0; off >>= 1) local += __shfl_down(local, off);
    if ((tid & 63) == 0) part[tid >> 6] = local;
    __syncthreads();
    if (tid == 0) {
        double sum = part[0] + part[1] + part[2] + part[3];
        out[QOFF + 1 + k] = (float)exp(sum);
        if (k == 0)
            out[QOFF] = (float)(1.25 * (*sse) / (double)NEL_);
    }
}

// ---------------------------------------------------------------------------
extern "C" void kernel_launch(void* const* d_in, const int* in_sizes, int n_in,
                              void* d_out, int out_size, void* d_ws, size_t ws_size,
                              hipStream_t stream) {
    const float* x  = (const float*)d_in[0];
    const float* cb = (const float*)d_in[1];
    float* out = (float*)d_out;

    float*         hcn    = (float*)((char*)d_ws + WS_HCN);
    int*           counts = (int*)((char*)d_ws + WS_CNT);
    double*        sse    = (double*)((char*)d_ws + WS_SSE);
    unsigned char* cbS    = (unsigned char*)((char*)d_ws + WS_CBS);

    hipMemsetAsync((char*)d_ws + WS_CNT, 0, 33024, stream);  // counts + sse

    vq_prep<<<(K_ * C_ * 8) / 256, 256, 0, stream>>>(cb, cbS, hcn);
    vq_main<<<B_ * K_ * (T_ / 256), 256, 0, stream>>>(x, cb, cbS, hcn,
                                                      out, counts, sse);
    vq_final<<<K_, 256, 0, stream>>>(counts, sse, out);
}